// Round 5
// baseline (222.069 us; speedup 1.0000x reference)
//
#include <hip/hip_runtime.h>
#include <math.h>

#define AS1 __attribute__((address_space(1)))
#define AS3 __attribute__((address_space(3)))

typedef __attribute__((ext_vector_type(8))) short bf16x8;
typedef __attribute__((ext_vector_type(4))) float f32x4;

__device__ __forceinline__ unsigned short f2bf(float f) {
    union { float f; unsigned int i; } v; v.f = f;
    unsigned int r = v.i + 0x7FFFu + ((v.i >> 16) & 1u);  // RNE
    return (unsigned short)(r >> 16);
}

// pack two fp32 -> packed bf16 pair (round-to-nearest; 3 VALU ops)
__device__ __forceinline__ unsigned int pack2bf(float lo, float hi) {
    union { float f; unsigned int i; } a, b; a.f = lo; b.f = hi;
    return __builtin_amdgcn_perm(b.i + 0x8000u, a.i + 0x8000u, 0x07060302u);
}

#define NTOK 1024
#define CCH  768
#define HD   64
#define QKS  1536   // qk buffer row stride (Q cols 0..767, K cols 768..1535)

// ---------------------------------------------------------------------------
// merged fp32 -> bf16 convert for x, qkv_w, proj_w (one launch)
// ---------------------------------------------------------------------------
#define N1C (8192 * 768 / 4)
#define N2C (2304 * 768 / 4)
#define N3C (768 * 768 / 4)

__global__ void cvt_all(const float* __restrict__ x, const float* __restrict__ w1,
                        const float* __restrict__ w2,
                        unsigned short* __restrict__ xb, unsigned short* __restrict__ w1b,
                        unsigned short* __restrict__ w2b)
{
    int i = blockIdx.x * blockDim.x + threadIdx.x;
    const float4* s; ushort4* d; int k;
    if (i < N1C)            { s = (const float4*)x;  d = (ushort4*)xb;  k = i; }
    else if (i < N1C + N2C) { s = (const float4*)w1; d = (ushort4*)w1b; k = i - N1C; }
    else if (i < N1C + N2C + N3C) { s = (const float4*)w2; d = (ushort4*)w2b; k = i - N1C - N2C; }
    else return;
    const float4 v = s[k];
    ushort4 o;
    o.x = f2bf(v.x); o.y = f2bf(v.y); o.z = f2bf(v.z); o.w = f2bf(v.w);
    d[k] = o;
}

// ---------------------------------------------------------------------------
// Proj GEMM: 64x128 tile (grid 128x6 = 768 blocks = 3/CU tail-free), fp32 out.
// 2-phase prefetch pipeline (BK=32 stages), one barrier/iter.
// ---------------------------------------------------------------------------
__global__ __launch_bounds__(256, 4)
void gemm_proj(const unsigned short* __restrict__ A,   // att [8192,768]
               const unsigned short* __restrict__ W,   // wpb [768,768]
               const float* __restrict__ bias,         // proj_b [768]
               float* __restrict__ Cmat)               // out [8192,768] fp32
{
    const int N = 768, K = 768;
    __shared__ __align__(16) unsigned short As[2][64 * 32];
    __shared__ __align__(16) unsigned short Bs[2][128 * 32];

    const int tid  = threadIdx.x;
    const int wave = tid >> 6;
    const int lane = tid & 63;
    const int quad = lane >> 4;
    const int l15  = lane & 15;
    const int wr   = wave >> 1;   // row-half (32 rows)
    const int wc   = wave & 1;    // col-half (64 cols)

    const int m0 = blockIdx.x * 64;
    const int n0 = blockIdx.y * 128;

    const unsigned short* AgS = A + (size_t)(m0 + wave * 16 + (lane >> 2)) * K + (lane & 3) * 8;
    const int srow = wave * 32 + (lane >> 2);
    const int scol = (lane & 3) * 8;
    const unsigned short* Wg0 = W + (size_t)(n0 + srow) * K + scol;
    const unsigned short* Wg1 = W + (size_t)(n0 + srow + 16) * K + scol;

    const int da  = wave * 512 + lane * 8;
    const int db0 = (wave * 2 + 0) * 512 + lane * 8;
    const int db1 = (wave * 2 + 1) * 512 + lane * 8;

    f32x4 acc[2][4];
#pragma unroll
    for (int i = 0; i < 2; ++i)
#pragma unroll
        for (int j = 0; j < 4; ++j) acc[i][j] = (f32x4){0.f, 0.f, 0.f, 0.f};

    __builtin_amdgcn_global_load_lds((AS1 void*)(AgS), (AS3 void*)(As[0] + da),  16, 0, 0);
    __builtin_amdgcn_global_load_lds((AS1 void*)(Wg0), (AS3 void*)(Bs[0] + db0), 16, 0, 0);
    __builtin_amdgcn_global_load_lds((AS1 void*)(Wg1), (AS3 void*)(Bs[0] + db1), 16, 0, 0);

#pragma unroll 2
    for (int kc = 0; kc < 24; ++kc) {
        const int cur = kc & 1;
        __syncthreads();
        if (kc < 23) {
            const int nk = (kc + 1) * 32;
            __builtin_amdgcn_global_load_lds((AS1 void*)(AgS + nk), (AS3 void*)(As[cur ^ 1] + da),  16, 0, 0);
            __builtin_amdgcn_global_load_lds((AS1 void*)(Wg0 + nk), (AS3 void*)(Bs[cur ^ 1] + db0), 16, 0, 0);
            __builtin_amdgcn_global_load_lds((AS1 void*)(Wg1 + nk), (AS3 void*)(Bs[cur ^ 1] + db1), 16, 0, 0);
        }

        bf16x8 af[2], bfr[4];
#pragma unroll
        for (int i = 0; i < 2; ++i)
            af[i] = *(const bf16x8*)(As[cur] + (wr * 32 + i * 16 + l15) * 32 + quad * 8);
#pragma unroll
        for (int j = 0; j < 4; ++j)
            bfr[j] = *(const bf16x8*)(Bs[cur] + (wc * 64 + j * 16 + l15) * 32 + quad * 8);
#pragma unroll
        for (int i = 0; i < 2; ++i)
#pragma unroll
            for (int j = 0; j < 4; ++j)
                acc[i][j] = __builtin_amdgcn_mfma_f32_16x16x32_bf16(af[i], bfr[j], acc[i][j], 0, 0, 0);
    }

#pragma unroll
    for (int i = 0; i < 2; ++i) {
        const int row = m0 + wr * 32 + i * 16 + quad * 4;
#pragma unroll
        for (int j = 0; j < 4; ++j) {
            const int col = n0 + wc * 64 + j * 16 + l15;
            const float bv = bias[col];
#pragma unroll
            for (int r = 0; r < 4; ++r)
                Cmat[(size_t)(row + r) * N + col] = acc[i][j][r] + bv;
        }
    }
}

// ---------------------------------------------------------------------------
// QKV GEMM v4 (r13 == r12 resubmit after infra failure): wave-autonomous,
// ZERO barriers in the K-loop. Block = 256 A-rows x 64 W-cols; grid 1152.
// W-slice (64x768 = 96 KB) staged to LDS ONCE (XOR bank-swizzle slot^=row&7,
// pre-swizzled global source, linear DMA dest), single __syncthreads, then
// LDS read-only: each wave runs an independent K-loop (32x64 strip, A-frags
// from global with 2-step register prefetch, 8 MFMA per K=32 step).
// ---------------------------------------------------------------------------
__global__ __launch_bounds__(512, 1)
void gemm_qkv(const unsigned short* __restrict__ A,   // xb [8192,768]
              const unsigned short* __restrict__ W,   // wqb [2304,768]
              const float* __restrict__ bias,         // qkv_b [2304]
              unsigned short* __restrict__ qk,        // [8192,1536]
              unsigned short* __restrict__ vT)        // [96*16*8*512]
{
    __shared__ __align__(16) unsigned short Bs[12 * 4096];   // 96 KB

    const int tid  = threadIdx.x;
    const int wave = tid >> 6;
    const int lane = tid & 63;
    const int quad = lane >> 4;
    const int l15  = lane & 15;

    // XCD swizzle: 1152 = 8 x 144; within an XCD chunk, nt varies fastest
    // (4 consecutive M-tiles x all 36 N-tiles per XCD).
    const int lin = blockIdx.x;                  // 0..1151
    const int idx = (lin & 7) * 144 + (lin >> 3);
    const int mt  = idx / 36;                    // 0..31
    const int nt  = idx % 36;                    // 0..35
    const int m0  = mt * 256;
    const int n0  = nt * 64;

    // --- stage W slice [n0..n0+63] x [0..767] into LDS, bank-swizzled ---
    // chunk c holds k in [c*64, c*64+64); layout [64 rows][8 slots of 16B];
    // logical slot sl stored at physical slot sl ^ (row & 7).
    {
        const int r  = tid >> 3;                 // 0..63
        const int sp = tid & 7;                  // physical slot this thread fills
        const int sl = sp ^ (r & 7);             // logical slot fetched
        const unsigned short* Wg = W + (size_t)(n0 + r) * 768 + sl * 8;
#pragma unroll
        for (int c = 0; c < 12; ++c)
            __builtin_amdgcn_global_load_lds((AS1 void*)(Wg + c * 64),
                (AS3 void*)(Bs + c * 4096 + tid * 8), 16, 0, 0);
    }

    // A-frag source: wave rows m0 + wave*32 + {0,16} + l15, k = st*32 + quad*8
    const unsigned short* Ag = A + (size_t)(m0 + wave * 32 + l15) * 768 + quad * 8;

    // swizzled B read offsets (elems): row = j*16 + l15, slot = (h*4+quad)^(l15&7)
    const int s0  = quad ^ (l15 & 7);
    const int bb0 = l15 * 64 + s0 * 8;           // h = 0 (k-low half of chunk)
    const int bb1 = l15 * 64 + (s0 ^ 4) * 8;     // h = 1 (k-high half)

    // prefetch A for steps 0,1 (global->VGPR; overlaps W staging)
    bf16x8 a0[2], a1[2];
    a0[0] = *(const bf16x8*)(Ag);
    a0[1] = *(const bf16x8*)(Ag + 12288);
    a1[0] = *(const bf16x8*)(Ag + 32);
    a1[1] = *(const bf16x8*)(Ag + 12288 + 32);

    f32x4 acc[2][4];
#pragma unroll
    for (int i = 0; i < 2; ++i)
#pragma unroll
        for (int j = 0; j < 4; ++j) acc[i][j] = (f32x4){0.f, 0.f, 0.f, 0.f};

    __syncthreads();   // implicit vmcnt(0): W resident; LDS read-only hereafter

    // K-loop: 12 chunks x 2 sub-steps (K=32 each), per-wave, barrier-free.
#define QKV_SUB(aReg, bb, cIdx, stNext) do {                                   \
    bf16x8 bF[4];                                                              \
    _Pragma("unroll")                                                          \
    for (int j = 0; j < 4; ++j)                                                \
        bF[j] = *(const bf16x8*)(Bs + (cIdx) * 4096 + j * 1024 + (bb));        \
    bf16x8 nA0, nA1;                                                           \
    if ((stNext) < 24) {                                                       \
        nA0 = *(const bf16x8*)(Ag + (stNext) * 32);                            \
        nA1 = *(const bf16x8*)(Ag + 12288 + (stNext) * 32);                    \
    }                                                                          \
    _Pragma("unroll")                                                          \
    for (int j = 0; j < 4; ++j)                                                \
        acc[0][j] = __builtin_amdgcn_mfma_f32_16x16x32_bf16(aReg[0], bF[j], acc[0][j], 0, 0, 0); \
    _Pragma("unroll")                                                          \
    for (int j = 0; j < 4; ++j)                                                \
        acc[1][j] = __builtin_amdgcn_mfma_f32_16x16x32_bf16(aReg[1], bF[j], acc[1][j], 0, 0, 0); \
    if ((stNext) < 24) { aReg[0] = nA0; aReg[1] = nA1; }                       \
} while (0)

#pragma unroll
    for (int s2 = 0; s2 < 12; ++s2) {
        QKV_SUB(a0, bb0, s2, 2 * s2 + 2);
        QKV_SUB(a1, bb1, s2, 2 * s2 + 3);
    }
#undef QKV_SUB

    // --- fused epilogue (zone uniform per BLOCK: n0 multiple of 64) ---
    if (n0 < 1536) {
        const float s = (n0 < 768) ? 0.125f : 1.f;
#pragma unroll
        for (int i = 0; i < 2; ++i) {
            const int row = m0 + wave * 32 + i * 16 + quad * 4;
#pragma unroll
            for (int j = 0; j < 4; ++j) {
                const int col = n0 + j * 16 + l15;
                const float bv = bias[col];
#pragma unroll
                for (int r = 0; r < 4; ++r)
                    qk[(size_t)(row + r) * QKS + col] = f2bf((acc[i][j][r] + bv) * s);
            }
        }
    } else {
        // V zone -> frag-linear vT
#pragma unroll
        for (int i = 0; i < 2; ++i) {
            const int m    = m0 + wave * 32 + i * 16 + quad * 4;
            const int b    = m >> 10;
            const int tok  = m & 1023;
            const int tile = tok >> 6;
            const int K0   = tok & 63;
#pragma unroll
            for (int j = 0; j < 4; ++j) {
                const int col = n0 + j * 16 + l15;
                const int c   = col - 1536;
                const int h   = c >> 6, d = c & 63;
                const float bv = bias[col];
                const int bh     = b * 12 + h;
                const int region = (d >> 4) * 2 + (K0 >> 5);
                const int L      = ((K0 >> 3) & 3) * 16 + (d & 15);
                uint2 o;
                o.x = pack2bf(acc[i][j][0] + bv, acc[i][j][1] + bv);
                o.y = pack2bf(acc[i][j][2] + bv, acc[i][j][3] + bv);
                *(uint2*)(vT + (((size_t)(bh * 16 + tile) * 8 + region) << 9) + L * 8 + (K0 & 7)) = o;
            }
        }
    }
}

// ---------------------------------------------------------------------------
// Flash attention v6 (unchanged): S^T formulation, no online max,
// Q pre-scaled, K/V double-buffered via global_load_lds DMA, 1 barrier/iter,
// PV in two 32-key passes, 40 KB LDS. XCD swizzle lin=qt*96+bh.
// ---------------------------------------------------------------------------
__global__ __launch_bounds__(256, 4)
void attn_fused(const unsigned short* __restrict__ qk,
                const unsigned short* __restrict__ vT,
                unsigned short* __restrict__ aout)
{
    __shared__ __align__(16) unsigned short Kf[2][8 * 512];
    __shared__ __align__(16) unsigned short Vt[2][8 * 512];
    __shared__ __align__(16) unsigned short Ps[8 * 512];

    const int tid  = threadIdx.x;
    const int wave = tid >> 6;
    const int lane = tid & 63;
    const int quad = lane >> 4;
    const int l15  = lane & 15;

    const int lin = blockIdx.x;          // 0..767
    const int bh  = lin % 96;
    const int qt  = lin / 96;            // 0..7
    const int b   = bh / 12;
    const int h   = bh % 12;

    const unsigned short* Qg  = qk + (size_t)b * NTOK * QKS + (size_t)h * HD;
    const unsigned short* Kg  = Qg + CCH;
    const unsigned short* vTb = vT + (size_t)bh * 16 * 8 * 512;

    const int q0 = qt * 128;

    bf16x8 qf[2][2];
#pragma unroll
    for (int qb = 0; qb < 2; ++qb)
#pragma unroll
        for (int ks = 0; ks < 2; ++ks)
            qf[qb][ks] = *(const bf16x8*)(Qg + (size_t)(q0 + wave * 32 + qb * 16 + l15) * QKS
                                              + ks * 32 + quad * 8);

    f32x4 oacc[2][4];
#pragma unroll
    for (int qb = 0; qb < 2; ++qb)
#pragma unroll
        for (int nb = 0; nb < 4; ++nb) oacc[qb][nb] = (f32x4){0.f, 0.f, 0.f, 0.f};
    float lrow[2] = {0.f, 0.f};

    const unsigned short* kdma = Kg + (size_t)(wave * 16 + l15) * QKS + quad * 8;

#pragma unroll
    for (int ks = 0; ks < 2; ++ks)
        __builtin_amdgcn_global_load_lds((AS1 void*)(kdma + ks * 32),
            (AS3 void*)(Kf[0] + (wave * 2 + ks) * 512 + lane * 8), 16, 0, 0);
#pragma unroll
    for (int u = 0; u < 2; ++u)
        __builtin_amdgcn_global_load_lds((AS1 void*)(vTb + (size_t)(wave * 2 + u) * 512 + lane * 8),
            (AS3 void*)(Vt[0] + (wave * 2 + u) * 512 + lane * 8), 16, 0, 0);

    for (int t = 0; t < 16; ++t) {
        const int cur = t & 1;
        __syncthreads();

        if (t < 15) {
            const int nxt = cur ^ 1;
#pragma unroll
            for (int ks = 0; ks < 2; ++ks)
                __builtin_amdgcn_global_load_lds((AS1 void*)(kdma + (size_t)((t + 1) * 64) * QKS + ks * 32),
                    (AS3 void*)(Kf[nxt] + (wave * 2 + ks) * 512 + lane * 8), 16, 0, 0);
#pragma unroll
            for (int u = 0; u < 2; ++u)
                __builtin_amdgcn_global_load_lds((AS1 void*)(vTb + ((size_t)(t + 1) * 8 + wave * 2 + u) * 512 + lane * 8),
                    (AS3 void*)(Vt[nxt] + (wave * 2 + u) * 512 + lane * 8), 16, 0, 0);
        }

        f32x4 sacc[2][4];
#pragma unroll
        for (int qb = 0; qb < 2; ++qb)
#pragma unroll
            for (int jk = 0; jk < 4; ++jk) sacc[qb][jk] = (f32x4){0.f, 0.f, 0.f, 0.f};
#pragma unroll
        for (int ks = 0; ks < 2; ++ks) {
            bf16x8 kf[4];
#pragma unroll
            for (int jk = 0; jk < 4; ++jk)
                kf[jk] = *(const bf16x8*)(Kf[cur] + (jk * 2 + ks) * 512 + lane * 8);
#pragma unroll
            for (int qb = 0; qb < 2; ++qb)
#pragma unroll
                for (int jk = 0; jk < 4; ++jk)
                    sacc[qb][jk] = __builtin_amdgcn_mfma_f32_16x16x32_bf16(
                        kf[jk], qf[qb][ks], sacc[qb][jk], 0, 0, 0);
        }

#pragma unroll
        for (int qb = 0; qb < 2; ++qb) {
            float rsum = 0.f;
#pragma unroll
            for (int jk = 0; jk < 4; ++jk)
#pragma unroll
                for (int r = 0; r < 4; ++r) {
                    const float p = __expf(sacc[qb][jk][r]);
                    sacc[qb][jk][r] = p;
                    rsum += p;
                }
            rsum += __shfl_xor(rsum, 16);
            rsum += __shfl_xor(rsum, 32);
            lrow[qb] += rsum;
        }

#pragma unroll
        for (int p = 0; p < 2; ++p) {
#pragma unroll
            for (int qb = 0; qb < 2; ++qb)
#pragma unroll
                for (int jh = 0; jh < 2; ++jh) {
                    const int jk = 2 * p + jh;
                    uint2 o;
                    o.x = pack2bf(sacc[qb][jk][0], sacc[qb][jk][1]);
                    o.y = pack2bf(sacc[qb][jk][2], sacc[qb][jk][3]);
                    const int off = (wave * 2 + qb) * 512
                                  + ((jh * 2 + (quad >> 1)) * 16 + l15) * 8 + (quad & 1) * 4;
                    *(uint2*)&Ps[off] = o;
                }
            bf16x8 pf[2], vf[4];
#pragma unroll
            for (int qb = 0; qb < 2; ++qb)
                pf[qb] = *(const bf16x8*)(Ps + (wave * 2 + qb) * 512 + lane * 8);
#pragma unroll
            for (int nb = 0; nb < 4; ++nb)
                vf[nb] = *(const bf16x8*)(Vt[cur] + (nb * 2 + p) * 512 + lane * 8);
#pragma unroll
            for (int qb = 0; qb < 2; ++qb)
#pragma unroll
                for (int nb = 0; nb < 4; ++nb)
                    oacc[qb][nb] = __builtin_amdgcn_mfma_f32_16x16x32_bf16(
                        vf[nb], pf[qb], oacc[qb][nb], 0, 0, 0);
        }
    }

#pragma unroll
    for (int qb = 0; qb < 2; ++qb) {
        const float inv = 1.f / lrow[qb];
        const size_t tok = (size_t)(b * NTOK + q0 + wave * 32 + qb * 16 + l15);
#pragma unroll
        for (int nb = 0; nb < 4; ++nb) {
            uint2 o;
            o.x = pack2bf(oacc[qb][nb][0] * inv, oacc[qb][nb][1] * inv);
            o.y = pack2bf(oacc[qb][nb][2] * inv, oacc[qb][nb][3] * inv);
            *(uint2*)(aout + tok * CCH + h * HD + nb * 16 + quad * 4) = o;
        }
    }
}

// ---------------------------------------------------------------------------
extern "C" void kernel_launch(void* const* d_in, const int* in_sizes, int n_in,
                              void* d_out, int out_size, void* d_ws, size_t ws_size,
                              hipStream_t stream)
{
    const float* x      = (const float*)d_in[0];  // [8192,768]
    const float* qkv_w  = (const float*)d_in[1];  // [2304,768]
    const float* qkv_b  = (const float*)d_in[2];  // [2304]
    const float* proj_w = (const float*)d_in[3];  // [768,768]
    const float* proj_b = (const float*)d_in[4];  // [768]
    float* out = (float*)d_out;                   // [8192,768] fp32

    unsigned short* qk  = (unsigned short*)d_ws;             // [8192,1536] bf16 (Q scaled, K)
    unsigned short* att = qk  + (size_t)8192 * 1536;         // [8192,768]
    unsigned short* xb  = att + (size_t)8192 * 768;          // [8192,768]
    unsigned short* wqb = xb  + (size_t)8192 * 768;          // [2304,768]
    unsigned short* wpb = wqb + (size_t)2304 * 768;          // [768,768]
    unsigned short* vT  = wpb + (size_t)768 * 768;           // frag-linear V^T [6.29M]

    cvt_all<<<dim3((N1C + N2C + N3C + 255) / 256), dim3(256), 0, stream>>>(x, qkv_w, proj_w, xb, wqb, wpb);
    gemm_qkv<<<dim3(1152), dim3(512), 0, stream>>>(xb, wqb, qkv_b, qk, vT);
    attn_fused<<<dim3(768), dim3(256), 0, stream>>>(qk, vT, att);
    gemm_proj<<<dim3(128, 6), dim3(256), 0, stream>>>(att, wpb, proj_b, out);
}

// Round 6
// 187.730 us; speedup vs baseline: 1.1829x; 1.1829x over previous
//
#include <hip/hip_runtime.h>
#include <math.h>

#define AS1 __attribute__((address_space(1)))
#define AS3 __attribute__((address_space(3)))

typedef __attribute__((ext_vector_type(8))) short bf16x8;
typedef __attribute__((ext_vector_type(4))) float f32x4;

__device__ __forceinline__ unsigned short f2bf(float f) {
    union { float f; unsigned int i; } v; v.f = f;
    unsigned int r = v.i + 0x7FFFu + ((v.i >> 16) & 1u);  // RNE
    return (unsigned short)(r >> 16);
}

// pack two fp32 -> packed bf16 pair (round-to-nearest; 3 VALU ops)
__device__ __forceinline__ unsigned int pack2bf(float lo, float hi) {
    union { float f; unsigned int i; } a, b; a.f = lo; b.f = hi;
    return __builtin_amdgcn_perm(b.i + 0x8000u, a.i + 0x8000u, 0x07060302u);
}

#define NTOK 1024
#define CCH  768
#define HD   64
#define QKS  1536   // qk buffer row stride (Q cols 0..767, K cols 768..1535)

// ---------------------------------------------------------------------------
// merged fp32 -> bf16 convert for x, qkv_w, proj_w (one launch)
// ---------------------------------------------------------------------------
#define N1C (8192 * 768 / 4)
#define N2C (2304 * 768 / 4)
#define N3C (768 * 768 / 4)

__global__ void cvt_all(const float* __restrict__ x, const float* __restrict__ w1,
                        const float* __restrict__ w2,
                        unsigned short* __restrict__ xb, unsigned short* __restrict__ w1b,
                        unsigned short* __restrict__ w2b)
{
    int i = blockIdx.x * blockDim.x + threadIdx.x;
    const float4* s; ushort4* d; int k;
    if (i < N1C)            { s = (const float4*)x;  d = (ushort4*)xb;  k = i; }
    else if (i < N1C + N2C) { s = (const float4*)w1; d = (ushort4*)w1b; k = i - N1C; }
    else if (i < N1C + N2C + N3C) { s = (const float4*)w2; d = (ushort4*)w2b; k = i - N1C - N2C; }
    else return;
    const float4 v = s[k];
    ushort4 o;
    o.x = f2bf(v.x); o.y = f2bf(v.y); o.z = f2bf(v.z); o.w = f2bf(v.w);
    d[k] = o;
}

// ---------------------------------------------------------------------------
// Proj GEMM v2 (r14): r3-proven 3-stage counted-vmcnt pipeline ported to the
// 64x128 tile (grid 768 linear = 3/CU streaming, nt-fastest XCD swizzle so 6
// consecutive blocks share one A-slice in L2). 256 thr / 4 waves (wave tile
// 32x64), BK=32, 3 loads/thread/stage -> vmcnt(3) keeps stage t+2 in flight
// across the barrier. T2 swizzle identical to r3 (row stride 64 B: XOR byte
// bits 4,5 with addr bits 7,8; pre-swizzled global src, linear DMA dest).
// LDS 36 KB -> 4 blocks/CU.
// ---------------------------------------------------------------------------
#define PROJ_STAGE(t, buf) do {                                                              \
    __builtin_amdgcn_global_load_lds((AS1 void*)(Ag  + (t) * 32), (AS3 void*)(Asx[buf] + dstA),  16, 0, 0); \
    __builtin_amdgcn_global_load_lds((AS1 void*)(Wg0 + (t) * 32), (AS3 void*)(Bsx[buf] + dstB0), 16, 0, 0); \
    __builtin_amdgcn_global_load_lds((AS1 void*)(Wg1 + (t) * 32), (AS3 void*)(Bsx[buf] + dstB1), 16, 0, 0); \
  } while (0)

#define PROJ_STEP(cur) do {                                                                  \
    bf16x8 af[2], bfv[4];                                                                    \
    _Pragma("unroll")                                                                        \
    for (int i = 0; i < 2; ++i)                                                              \
        af[i] = *(const bf16x8*)((const char*)&Asx[0][0] + (cur) * 4096 + dA + i * 1024);    \
    _Pragma("unroll")                                                                        \
    for (int j = 0; j < 4; ++j)                                                              \
        bfv[j] = *(const bf16x8*)((const char*)&Bsx[0][0] + (cur) * 8192 + dB + j * 1024);   \
    __builtin_amdgcn_s_setprio(1);                                                           \
    _Pragma("unroll")                                                                        \
    for (int i = 0; i < 2; ++i)                                                              \
      _Pragma("unroll")                                                                      \
      for (int j = 0; j < 4; ++j)                                                            \
        acc[i][j] = __builtin_amdgcn_mfma_f32_16x16x32_bf16(af[i], bfv[j], acc[i][j], 0, 0, 0); \
    __builtin_amdgcn_s_setprio(0);                                                           \
  } while (0)

__global__ __launch_bounds__(256, 4)
void gemm_proj(const unsigned short* __restrict__ A,   // att [8192,768]
               const unsigned short* __restrict__ W,   // wpb [768,768]
               const float* __restrict__ bias,         // proj_b [768]
               float* __restrict__ Cmat)               // out [8192,768] fp32
{
    const int N = 768, K = 768;
    __shared__ __align__(16) unsigned short Asx[3][64 * 32];    // 12 KB
    __shared__ __align__(16) unsigned short Bsx[3][128 * 32];   // 24 KB

    const int tid  = threadIdx.x;
    const int wave = tid >> 6;
    const int lane = tid & 63;
    const int quad = lane >> 4;
    const int l15  = lane & 15;
    const int wr   = wave >> 1;   // row-half (32 rows)
    const int wc   = wave & 1;    // col-half (64 cols)

    // XCD swizzle, nt fastest: 6 consecutive blocks on one XCD share A-slice.
    const int lin = blockIdx.x;                 // 0..767
    const int idx = (lin & 7) * 96 + (lin >> 3);
    const int mt  = idx / 6;                    // 0..127
    const int nt  = idx % 6;                    // 0..5
    const int m0  = mt * 64;
    const int n0  = nt * 128;

    // --- staging source (pre-swizzled col so linear DMA dest works) ---
    const int r  = tid >> 2;                    // 0..63
    const int sp = tid & 3;                     // physical 16B slot
    const int sl = sp ^ ((r >> 1) & 3);         // logical slot fetched
    const unsigned short* Ag  = A + (size_t)(m0 + r)      * K + sl * 8;
    const unsigned short* Wg0 = W + (size_t)(n0 + r)      * K + sl * 8;
    const unsigned short* Wg1 = W + (size_t)(n0 + 64 + r) * K + sl * 8;
    const int dstA  = tid * 8;                  // elems (linear, 16B/thread)
    const int dstB0 = tid * 8;
    const int dstB1 = tid * 8 + 2048;

    // --- swizzled ds_read base offsets (XOR bits 4,5 with addr bits 7,8) ---
    int dA = (wr * 32 + l15) * 64 + quad * 16;
    dA ^= ((dA >> 7) & 1) << 4;  dA ^= ((dA >> 8) & 1) << 5;
    int dB = (wc * 64 + l15) * 64 + quad * 16;
    dB ^= ((dB >> 7) & 1) << 4;  dB ^= ((dB >> 8) & 1) << 5;

    f32x4 acc[2][4];
#pragma unroll
    for (int i = 0; i < 2; ++i)
#pragma unroll
        for (int j = 0; j < 4; ++j) acc[i][j] = (f32x4){0.f, 0.f, 0.f, 0.f};

    // prologue: tiles 0,1 staged; wait tile 0 (own 3 loads), barrier
    PROJ_STAGE(0, 0);
    PROJ_STAGE(1, 1);
    asm volatile("s_waitcnt vmcnt(3)" ::: "memory");
    __builtin_amdgcn_s_barrier();
    __builtin_amdgcn_sched_barrier(0);

#pragma unroll
    for (int t = 0; t < 22; ++t) {
        const int cur = t % 3;
        PROJ_STAGE(t + 2, (t + 2) % 3);      // into buffer last read at t-1
        __builtin_amdgcn_sched_barrier(0);   // keep issue early
        PROJ_STEP(cur);
        asm volatile("s_waitcnt vmcnt(3)" ::: "memory");  // t+1 landed; t+2 flies on
        __builtin_amdgcn_s_barrier();
        __builtin_amdgcn_sched_barrier(0);   // nothing hoists above barrier
    }
    // t = 22 (cur = 1): no stage left
    PROJ_STEP(1);
    asm volatile("s_waitcnt vmcnt(0)" ::: "memory");      // tile 23 landed
    __builtin_amdgcn_s_barrier();
    __builtin_amdgcn_sched_barrier(0);
    // t = 23 (cur = 2)
    PROJ_STEP(2);

#pragma unroll
    for (int i = 0; i < 2; ++i) {
        const int row = m0 + wr * 32 + i * 16 + quad * 4;
#pragma unroll
        for (int j = 0; j < 4; ++j) {
            const int col = n0 + wc * 64 + j * 16 + l15;
            const float bv = bias[col];
#pragma unroll
            for (int r2 = 0; r2 < 4; ++r2)
                Cmat[(size_t)(row + r2) * N + col] = acc[i][j][r2] + bv;
        }
    }
}

// ---------------------------------------------------------------------------
// QKV GEMM v3 (r3 verbatim — best measured: 47.6 us, 0 bank conflicts):
// 256x128 tile, 512 thr (8 waves, 4Mx2N -> wave 64x64), BK=32 TRIPLE-buffered
// pipeline, counted vmcnt(3) across raw s_barrier (T4), T2 LDS swizzle
// (pre-swizzled global src + swizzled ds_read, linear DMA dest), T5 setprio.
// LDS 72 KB -> 2 blocks/CU. Grid 576 = 32x18, 2-D XCD region swizzle.
// ---------------------------------------------------------------------------
#define QKV_STAGE(t, buf) do {                                                               \
    __builtin_amdgcn_global_load_lds((AS1 void*)(Ag0 + (t) * 32), (AS3 void*)(As[buf] + dst0), 16, 0, 0); \
    __builtin_amdgcn_global_load_lds((AS1 void*)(Ag1 + (t) * 32), (AS3 void*)(As[buf] + dst1), 16, 0, 0); \
    __builtin_amdgcn_global_load_lds((AS1 void*)(Wg0 + (t) * 32), (AS3 void*)(Bs[buf] + dstB), 16, 0, 0); \
  } while (0)

#define QKV_STEP(cur) do {                                                                   \
    bf16x8 af[4], bfv[4];                                                                    \
    _Pragma("unroll")                                                                        \
    for (int i = 0; i < 4; ++i)                                                              \
        af[i] = *(const bf16x8*)((const char*)&As[0][0] + (cur) * 16384 + dA + i * 1024);    \
    _Pragma("unroll")                                                                        \
    for (int j = 0; j < 4; ++j)                                                              \
        bfv[j] = *(const bf16x8*)((const char*)&Bs[0][0] + (cur) * 8192 + dB + j * 1024);    \
    __builtin_amdgcn_s_setprio(1);                                                           \
    _Pragma("unroll")                                                                        \
    for (int i = 0; i < 4; ++i)                                                              \
      _Pragma("unroll")                                                                      \
      for (int j = 0; j < 4; ++j)                                                            \
        acc[i][j] = __builtin_amdgcn_mfma_f32_16x16x32_bf16(af[i], bfv[j], acc[i][j], 0, 0, 0); \
    __builtin_amdgcn_s_setprio(0);                                                           \
  } while (0)

__global__ __launch_bounds__(512, 4)
void gemm_qkv(const unsigned short* __restrict__ A,   // xb [8192,768]
              const unsigned short* __restrict__ W,   // wqb [2304,768]
              const float* __restrict__ bias,         // qkv_b [2304]
              unsigned short* __restrict__ qk,        // [8192,1536]
              unsigned short* __restrict__ vT)        // [96*16*8*512]
{
    const int K = 768;
    __shared__ __align__(16) unsigned short As[3][256 * 32];   // 48 KB
    __shared__ __align__(16) unsigned short Bs[3][128 * 32];   // 24 KB

    const int tid  = threadIdx.x;
    const int wave = tid >> 6;
    const int lane = tid & 63;
    const int quad = lane >> 4;
    const int l15  = lane & 15;
    const int wr   = wave >> 1;   // 0..3  (64-row quarter)
    const int wc   = wave & 1;    // 0..1  (64-col half)

    // 2-D XCD region swizzle: xcd = lin&7 laid out 4x2; each XCD covers an
    // 8(bx) x 9(by) rectangle -> per-XCD working set ~= 3.1 MB A + 1.7 MB W.
    const int lin = blockIdx.x;                 // 0..575
    const int xcd = lin & 7;
    const int j9  = lin >> 3;                   // 0..71
    const int bx  = (xcd & 3) * 8 + (j9 & 7);   // 0..31
    const int by  = (xcd >> 2) * 9 + (j9 >> 3); // 0..17
    const int m0  = bx * 256;
    const int n0  = by * 128;

    // --- staging source (pre-swizzled global col so linear DMA dest works) ---
    const int srow  = tid >> 2;                                  // 0..127
    const int scolb = ((tid & 3) << 4)
                    ^ (((tid >> 3) & 1) << 4)
                    ^ (((tid >> 4) & 1) << 5);                   // byte col 0..63
    const unsigned short* Ag0 = A + (size_t)(m0 + srow)       * K + (scolb >> 1);
    const unsigned short* Ag1 = A + (size_t)(m0 + 128 + srow) * K + (scolb >> 1);
    const unsigned short* Wg0 = W + (size_t)(n0 + srow)       * K + (scolb >> 1);
    const int dst0 = tid * 8;            // elems (linear LDS dest, lane*16B)
    const int dst1 = tid * 8 + 4096;
    const int dstB = tid * 8;

    // --- swizzled ds_read base offsets (bits 7,8 depend only on l15) ---
    int dA = (wr * 64 + l15) * 64 + quad * 16;
    dA ^= ((dA >> 7) & 1) << 4;  dA ^= ((dA >> 8) & 1) << 5;
    int dB = (wc * 64 + l15) * 64 + quad * 16;
    dB ^= ((dB >> 7) & 1) << 4;  dB ^= ((dB >> 8) & 1) << 5;

    f32x4 acc[4][4];
#pragma unroll
    for (int i = 0; i < 4; ++i)
#pragma unroll
        for (int j = 0; j < 4; ++j) acc[i][j] = (f32x4){0.f, 0.f, 0.f, 0.f};

    // prologue: tiles 0,1 staged; wait tile 0 (3 own loads), barrier
    QKV_STAGE(0, 0);
    QKV_STAGE(1, 1);
    asm volatile("s_waitcnt vmcnt(3)" ::: "memory");
    __builtin_amdgcn_s_barrier();
    __builtin_amdgcn_sched_barrier(0);

#pragma unroll
    for (int t = 0; t < 22; ++t) {
        const int cur = t % 3;
        QKV_STAGE(t + 2, (t + 2) % 3);       // into buffer last read at t-1
        __builtin_amdgcn_sched_barrier(0);   // keep issue early
        QKV_STEP(cur);
        asm volatile("s_waitcnt vmcnt(3)" ::: "memory");  // t+1 landed; t+2 flies on
        __builtin_amdgcn_s_barrier();
        __builtin_amdgcn_sched_barrier(0);   // nothing hoists above barrier
    }
    // t = 22 (cur = 1): no stage left
    QKV_STEP(1);
    asm volatile("s_waitcnt vmcnt(0)" ::: "memory");      // tile 23 landed
    __builtin_amdgcn_s_barrier();
    __builtin_amdgcn_sched_barrier(0);
    // t = 23 (cur = 2)
    QKV_STEP(2);

    // --- fused epilogue (zones uniform per wave: colbase multiple of 64) ---
    const int colbase = n0 + wc * 64;
    if (colbase < 1536) {
        const float s = (colbase < 768) ? 0.125f : 1.f;
#pragma unroll
        for (int i = 0; i < 4; ++i) {
            const int row = m0 + wr * 64 + i * 16 + quad * 4;
#pragma unroll
            for (int j = 0; j < 4; ++j) {
                const int col = colbase + j * 16 + l15;
                const float bv = bias[col];
#pragma unroll
                for (int r = 0; r < 4; ++r)
                    qk[(size_t)(row + r) * QKS + col] = f2bf((acc[i][j][r] + bv) * s);
            }
        }
    } else {
        // V zone -> frag-linear vT
#pragma unroll
        for (int i = 0; i < 4; ++i) {
            const int m    = m0 + wr * 64 + i * 16 + quad * 4;
            const int b    = m >> 10;
            const int tok  = m & 1023;
            const int tile = tok >> 6;
            const int K0   = tok & 63;
#pragma unroll
            for (int j = 0; j < 4; ++j) {
                const int col = colbase + j * 16 + l15;
                const int c   = col - 1536;
                const int h   = c >> 6, d = c & 63;
                const float bv = bias[col];
                const int bh     = b * 12 + h;
                const int region = (d >> 4) * 2 + (K0 >> 5);
                const int L      = ((K0 >> 3) & 3) * 16 + (d & 15);
                uint2 o;
                o.x = pack2bf(acc[i][j][0] + bv, acc[i][j][1] + bv);
                o.y = pack2bf(acc[i][j][2] + bv, acc[i][j][3] + bv);
                *(uint2*)(vT + (((size_t)(bh * 16 + tile) * 8 + region) << 9) + L * 8 + (K0 & 7)) = o;
            }
        }
    }
}

// ---------------------------------------------------------------------------
// Flash attention v6 (unchanged): S^T formulation, no online max,
// Q pre-scaled, K/V double-buffered via global_load_lds DMA, 1 barrier/iter,
// PV in two 32-key passes, 40 KB LDS. XCD swizzle lin=qt*96+bh.
// ---------------------------------------------------------------------------
__global__ __launch_bounds__(256, 4)
void attn_fused(const unsigned short* __restrict__ qk,
                const unsigned short* __restrict__ vT,
                unsigned short* __restrict__ aout)
{
    __shared__ __align__(16) unsigned short Kf[2][8 * 512];
    __shared__ __align__(16) unsigned short Vt[2][8 * 512];
    __shared__ __align__(16) unsigned short Ps[8 * 512];

    const int tid  = threadIdx.x;
    const int wave = tid >> 6;
    const int lane = tid & 63;
    const int quad = lane >> 4;
    const int l15  = lane & 15;

    const int lin = blockIdx.x;          // 0..767
    const int bh  = lin % 96;
    const int qt  = lin / 96;            // 0..7
    const int b   = bh / 12;
    const int h   = bh % 12;

    const unsigned short* Qg  = qk + (size_t)b * NTOK * QKS + (size_t)h * HD;
    const unsigned short* Kg  = Qg + CCH;
    const unsigned short* vTb = vT + (size_t)bh * 16 * 8 * 512;

    const int q0 = qt * 128;

    bf16x8 qf[2][2];
#pragma unroll
    for (int qb = 0; qb < 2; ++qb)
#pragma unroll
        for (int ks = 0; ks < 2; ++ks)
            qf[qb][ks] = *(const bf16x8*)(Qg + (size_t)(q0 + wave * 32 + qb * 16 + l15) * QKS
                                              + ks * 32 + quad * 8);

    f32x4 oacc[2][4];
#pragma unroll
    for (int qb = 0; qb < 2; ++qb)
#pragma unroll
        for (int nb = 0; nb < 4; ++nb) oacc[qb][nb] = (f32x4){0.f, 0.f, 0.f, 0.f};
    float lrow[2] = {0.f, 0.f};

    const unsigned short* kdma = Kg + (size_t)(wave * 16 + l15) * QKS + quad * 8;

#pragma unroll
    for (int ks = 0; ks < 2; ++ks)
        __builtin_amdgcn_global_load_lds((AS1 void*)(kdma + ks * 32),
            (AS3 void*)(Kf[0] + (wave * 2 + ks) * 512 + lane * 8), 16, 0, 0);
#pragma unroll
    for (int u = 0; u < 2; ++u)
        __builtin_amdgcn_global_load_lds((AS1 void*)(vTb + (size_t)(wave * 2 + u) * 512 + lane * 8),
            (AS3 void*)(Vt[0] + (wave * 2 + u) * 512 + lane * 8), 16, 0, 0);

    for (int t = 0; t < 16; ++t) {
        const int cur = t & 1;
        __syncthreads();

        if (t < 15) {
            const int nxt = cur ^ 1;
#pragma unroll
            for (int ks = 0; ks < 2; ++ks)
                __builtin_amdgcn_global_load_lds((AS1 void*)(kdma + (size_t)((t + 1) * 64) * QKS + ks * 32),
                    (AS3 void*)(Kf[nxt] + (wave * 2 + ks) * 512 + lane * 8), 16, 0, 0);
#pragma unroll
            for (int u = 0; u < 2; ++u)
                __builtin_amdgcn_global_load_lds((AS1 void*)(vTb + ((size_t)(t + 1) * 8 + wave * 2 + u) * 512 + lane * 8),
                    (AS3 void*)(Vt[nxt] + (wave * 2 + u) * 512 + lane * 8), 16, 0, 0);
        }

        f32x4 sacc[2][4];
#pragma unroll
        for (int qb = 0; qb < 2; ++qb)
#pragma unroll
            for (int jk = 0; jk < 4; ++jk) sacc[qb][jk] = (f32x4){0.f, 0.f, 0.f, 0.f};
#pragma unroll
        for (int ks = 0; ks < 2; ++ks) {
            bf16x8 kf[4];
#pragma unroll
            for (int jk = 0; jk < 4; ++jk)
                kf[jk] = *(const bf16x8*)(Kf[cur] + (jk * 2 + ks) * 512 + lane * 8);
#pragma unroll
            for (int qb = 0; qb < 2; ++qb)
#pragma unroll
                for (int jk = 0; jk < 4; ++jk)
                    sacc[qb][jk] = __builtin_amdgcn_mfma_f32_16x16x32_bf16(
                        kf[jk], qf[qb][ks], sacc[qb][jk], 0, 0, 0);
        }

#pragma unroll
        for (int qb = 0; qb < 2; ++qb) {
            float rsum = 0.f;
#pragma unroll
            for (int jk = 0; jk < 4; ++jk)
#pragma unroll
                for (int r = 0; r < 4; ++r) {
                    const float p = __expf(sacc[qb][jk][r]);
                    sacc[qb][jk][r] = p;
                    rsum += p;
                }
            rsum += __shfl_xor(rsum, 16);
            rsum += __shfl_xor(rsum, 32);
            lrow[qb] += rsum;
        }

#pragma unroll
        for (int p = 0; p < 2; ++p) {
#pragma unroll
            for (int qb = 0; qb < 2; ++qb)
#pragma unroll
                for (int jh = 0; jh < 2; ++jh) {
                    const int jk = 2 * p + jh;
                    uint2 o;
                    o.x = pack2bf(sacc[qb][jk][0], sacc[qb][jk][1]);
                    o.y = pack2bf(sacc[qb][jk][2], sacc[qb][jk][3]);
                    const int off = (wave * 2 + qb) * 512
                                  + ((jh * 2 + (quad >> 1)) * 16 + l15) * 8 + (quad & 1) * 4;
                    *(uint2*)&Ps[off] = o;
                }
            bf16x8 pf[2], vf[4];
#pragma unroll
            for (int qb = 0; qb < 2; ++qb)
                pf[qb] = *(const bf16x8*)(Ps + (wave * 2 + qb) * 512 + lane * 8);
#pragma unroll
            for (int nb = 0; nb < 4; ++nb)
                vf[nb] = *(const bf16x8*)(Vt[cur] + (nb * 2 + p) * 512 + lane * 8);
#pragma unroll
            for (int qb = 0; qb < 2; ++qb)
#pragma unroll
                for (int nb = 0; nb < 4; ++nb)
                    oacc[qb][nb] = __builtin_amdgcn_mfma_f32_16x16x32_bf16(
                        vf[nb], pf[qb], oacc[qb][nb], 0, 0, 0);
        }
    }

#pragma unroll
    for (int qb = 0; qb < 2; ++qb) {
        const float inv = 1.f / lrow[qb];
        const size_t tok = (size_t)(b * NTOK + q0 + wave * 32 + qb * 16 + l15);
#pragma unroll
        for (int nb = 0; nb < 4; ++nb) {
            uint2 o;
            o.x = pack2bf(oacc[qb][nb][0] * inv, oacc[qb][nb][1] * inv);
            o.y = pack2bf(oacc[qb][nb][2] * inv, oacc[qb][nb][3] * inv);
            *(uint2*)(aout + tok * CCH + h * HD + nb * 16 + quad * 4) = o;
        }
    }
}

// ---------------------------------------------------------------------------
extern "C" void kernel_launch(void* const* d_in, const int* in_sizes, int n_in,
                              void* d_out, int out_size, void* d_ws, size_t ws_size,
                              hipStream_t stream)
{
    const float* x      = (const float*)d_in[0];  // [8192,768]
    const float* qkv_w  = (const float*)d_in[1];  // [2304,768]
    const float* qkv_b  = (const float*)d_in[2];  // [2304]
    const float* proj_w = (const float*)d_in[3];  // [768,768]
    const float* proj_b = (const float*)d_in[4];  // [768]
    float* out = (float*)d_out;                   // [8192,768] fp32

    unsigned short* qk  = (unsigned short*)d_ws;             // [8192,1536] bf16 (Q scaled, K)
    unsigned short* att = qk  + (size_t)8192 * 1536;         // [8192,768]
    unsigned short* xb  = att + (size_t)8192 * 768;          // [8192,768]
    unsigned short* wqb = xb  + (size_t)8192 * 768;          // [2304,768]
    unsigned short* wpb = wqb + (size_t)2304 * 768;          // [768,768]
    unsigned short* vT  = wpb + (size_t)768 * 768;           // frag-linear V^T [6.29M]

    cvt_all<<<dim3((N1C + N2C + N3C + 255) / 256), dim3(256), 0, stream>>>(x, qkv_w, proj_w, xb, wqb, wpb);
    gemm_qkv<<<dim3(576), dim3(512), 0, stream>>>(xb, wqb, qkv_b, qk, vT);
    attn_fused<<<dim3(768), dim3(256), 0, stream>>>(qk, vT, att);
    gemm_proj<<<dim3(768), dim3(256), 0, stream>>>(att, wpb, proj_b, out);
}